// Round 7
// baseline (14039.864 us; speedup 1.0000x reference)
//
#include <hip/hip_runtime.h>
#include <hip/hip_bf16.h>

// Jordan RNN restructured:
//   Wc = Wyh @ Wout  [H,H]
//   pre[b,t,:] = emb@Whx^T + bhx + byh + (t==0 ? last_logits@Wyh^T : Wyh@bout)
//   scan: h_t = tanh(pre_t + h_{t-1} @ Wc^T)     (per-batch independent)
//   y_t  = h_t @ Wout^T + bout                    (time-parallel epilogue GEMM)
//
// Scan (this round): N-SPLIT across 8 CUs. WG pair (2p,2p+1) owns batches
// [16p,16p+16); side s computes cols [256s,256s+256). Each side's Wc-half
// (256KB) is fully VGPR-pinned (128 regs/wave) -> zero steady-state Wc traffic.
// h halves are exchanged through the bf16 h-store in d_out itself, packed at
// u16 index (row*1024 + 256 + col) so each side's h lands inside its OWN pre
// byte-region (no cross-WG aliasing). Per-step pairwise flag sync:
// producer: threadfence -> syncthreads -> tid0 release-store flag=t
// consumer: acquire-spin flag>=t-1 at step top, then load partner A-frags
// directly from global (16B row-contiguous = exact MFMA A fragment layout).

#define NB 64
#define NT 2048
#define ND 512
#define NH 512
#define NO 512
#define TH (NT * NH)

typedef float f32x4 __attribute__((ext_vector_type(4)));
typedef __bf16 bf16x8 __attribute__((ext_vector_type(8)));
typedef unsigned short u16x8 __attribute__((ext_vector_type(8)));

__device__ __forceinline__ unsigned short f2bf(float x) {
  unsigned u = __builtin_bit_cast(unsigned, x);
  u += 0x7FFFu + ((u >> 16) & 1u);               // RNE
  return (unsigned short)(u >> 16);
}
__device__ __forceinline__ bf16x8 ld_frag(const unsigned short* p) {
  u16x8 r = *(const u16x8*)p;
  return __builtin_bit_cast(bf16x8, r);
}
__device__ __forceinline__ f32x4 ld_frag4(const unsigned short* p) {
  return *(const f32x4*)p;
}
// tanh via hardware exp2/rcp: abs err ~1e-6, inf-safe.
__device__ __forceinline__ float fast_tanh(float x) {
  float ax = __builtin_fabsf(x);
  float e = __builtin_amdgcn_exp2f(ax * 2.8853900817779268f);  // e^(2|x|)
  float r = 1.0f - 2.0f * __builtin_amdgcn_rcpf(e + 1.0f);
  return __builtin_copysignf(r, x);
}

// ---------------- prep kernels ----------------

// also re-initializes the scan sync flags every launch (deterministic replay)
__global__ void k_bias(const float* __restrict__ Wyh, const float* __restrict__ bout,
                       const float* __restrict__ bhx, const float* __restrict__ byh,
                       float* bias_t0, float* bias_t, int* flags) {
  int j = threadIdx.x;
  if (j < 128) flags[j] = -1;
  const float* row = Wyh + j * NO;
  float acc = 0.f;
  for (int o = 0; o < NO; ++o) acc += row[o] * bout[o];
  bias_t0[j] = bhx[j] + byh[j];
  bias_t[j]  = bhx[j] + byh[j] + acc;
}

__global__ void k_z0(const float* __restrict__ ll, const float* __restrict__ Wyh,
                     float* z0) {
  int b = blockIdx.x, j = threadIdx.x;
  const float* row = Wyh + j * NO;
  const float* lr = ll + b * NO;
  float acc = 0.f;
  for (int o = 0; o < NO; ++o) acc += lr[o] * row[o];
  z0[b * NH + j] = acc;
}

__global__ void k_wc(const float* __restrict__ Wyh, const float* __restrict__ Wout,
                     float* Wc) {
  int j = blockIdx.x, k = threadIdx.x;
  float acc = 0.f;
  for (int o = 0; o < NO; ++o) acc += Wyh[j * NO + o] * Wout[o * NH + k];
  Wc[j * NH + k] = acc;
}

// Build MFMA B-operand fragments for Bm = src^T (src is [N=512 rows][K=512 cols]).
// Fragment for 16x16x32: lane l holds B[kt*32 + (l>>4)*8 + i][nt*16 + (l&15)], i=0..7.
__global__ void k_frag(const float* __restrict__ src, unsigned short* __restrict__ dst) {
  int gid = blockIdx.x * 256 + threadIdx.x;  // 32768 total
  int lane = gid & 63, tidx = gid >> 6;
  int nt = tidx & 31, kt = tidx >> 5;
  const float* s = src + (size_t)(nt * 16 + (lane & 15)) * 512 + kt * 32 + (lane >> 4) * 8;
  unsigned short* d = dst + (size_t)gid * 8;
#pragma unroll
  for (int i = 0; i < 8; ++i) d[i] = f2bf(s[i]);
}

// ---------------- big GEMM (P1 and P3) ----------------
// MODE 0 (P1): A fp32 (emb); bias = (t==0 ? bias_t0+z0 : bias_t)
// MODE 1 (P3): A bf16 packed at u16 index row*1024 + 256 + c (h from scan);
//              bias = bout; in-place (A aliases out); t==T-1 rows -> last[]
template <int MODE>
__global__ __launch_bounds__(512) void k_gemm(
    const void* __restrict__ Ain, const unsigned short* __restrict__ fragB,
    float* __restrict__ out, const float* __restrict__ bias_t0,
    const float* __restrict__ bias_t, const float* __restrict__ z0,
    const float* __restrict__ bout, float* __restrict__ last) {
  __shared__ __align__(16) unsigned short a_lds[64 * 512];  // 64KB, XOR-swizzled bf16
  int tid = threadIdx.x;
  long bt0 = (long)blockIdx.x * 64;

  if (MODE == 0) {
    const float* A = (const float*)Ain;
#pragma unroll
    for (int it = 0; it < 16; ++it) {
      int chunk = it * 512 + tid;
      int r = chunk >> 7, c4 = chunk & 127;
      float4 v = ((const float4*)A)[(bt0 + r) * 128 + c4];
      int idx = (r * 512 + c4 * 4) ^ ((r & 7) << 3);
      unsigned short* p = &a_lds[idx];
      p[0] = f2bf(v.x); p[1] = f2bf(v.y); p[2] = f2bf(v.z); p[3] = f2bf(v.w);
    }
  } else {
    const unsigned short* A = (const unsigned short*)Ain;
#pragma unroll
    for (int it = 0; it < 8; ++it) {
      int chunk = it * 512 + tid;           // 4096 chunks of 8 u16
      int r = chunk >> 6, c8 = chunk & 63;
      u16x8 v = *(const u16x8*)(A + (size_t)(bt0 + r) * 1024 + 256 + c8 * 8);
      int idx = (r * 512 + c8 * 8) ^ ((r & 7) << 3);
      *(u16x8*)&a_lds[idx] = v;
    }
  }
  __syncthreads();

  int wave = tid >> 6, lane = tid & 63;
  int r0 = (wave & 3) * 16, c0 = (wave >> 2) * 256;
  f32x4 acc[16];
#pragma unroll
  for (int n = 0; n < 16; ++n) acc[n] = (f32x4){0.f, 0.f, 0.f, 0.f};
  int arow = r0 + (lane & 15);

  for (int kt = 0; kt < 16; ++kt) {
    int aidx = (arow * 512 + kt * 32 + (lane >> 4) * 8) ^ ((arow & 7) << 3);
    bf16x8 a = ld_frag(&a_lds[aidx]);
    const unsigned short* bp = fragB + ((size_t)(kt * 32 + (c0 >> 4)) * 64 + lane) * 8;
#pragma unroll
    for (int n = 0; n < 16; ++n) {
      bf16x8 b = ld_frag(bp + (size_t)n * 512);
      acc[n] = __builtin_amdgcn_mfma_f32_16x16x32_bf16(a, b, acc[n], 0, 0, 0);
    }
  }

#pragma unroll
  for (int n = 0; n < 16; ++n) {
    int col = c0 + n * 16 + (lane & 15);
#pragma unroll
    for (int reg = 0; reg < 4; ++reg) {
      long row = bt0 + r0 + (lane >> 4) * 4 + reg;
      float v = acc[n][reg];
      if (MODE == 0) {
        int t = (int)(row & (NT - 1));
        long b = row >> 11;
        v += (t == 0) ? (bias_t0[col] + z0[b * NH + col]) : bias_t[col];
      } else {
        v += bout[col];
      }
      out[row * 512 + col] = v;
      if (MODE == 1 && ((row & (NT - 1)) == NT - 1)) last[(row >> 11) * 512 + col] = v;
    }
  }
}

// ---------------- sequential scan (paired N-split) ----------------
// grid 8 x 512. WG = (pair, side). Own h half cross-wave via 16KB LDS dbuf;
// partner h half via global bf16 h-store + flag handshake.
__global__ __launch_bounds__(512, 2) void k_scan(float* __restrict__ buf,
                                                 const unsigned short* __restrict__ fragWc,
                                                 int* __restrict__ flags) {
  __shared__ __align__(16) unsigned short h_lds[2][16 * 256];  // 16KB
  unsigned short* hbuf = (unsigned short*)buf;
  const int tid = threadIdx.x;
  const int pair = blockIdx.x >> 1, side = blockIdx.x & 1;
  const int b0 = pair * 16;
  const int C0 = side * 256, Cp = 256 - C0;
  const int wave = tid >> 6, lane = tid & 63;
  const int arow = lane & 15, bb = lane >> 4;
  const int cw0 = wave * 32;                 // own-half col base for this wave
  const int swz = (arow & 7) << 3;
  int* flagO = flags + (pair * 2 + side) * 16;
  int* flagP = flags + (pair * 2 + (1 - side)) * 16;

  // ---- pinned Wc fragments: br[g][n]; g<8 = own kt groups (k in own cols),
  //      g>=8 = partner kt groups. Static indexing everywhere (rule #20).
  const int nt0 = (C0 >> 4) + 2 * wave;
  f32x4 br[16][2];
#pragma unroll
  for (int g = 0; g < 16; ++g) {
    int ktg = (g < 8) ? (8 * side + g) : (8 * (1 - side) + (g - 8));
#pragma unroll
    for (int n = 0; n < 2; ++n)
      br[g][n] = ld_frag4(fragWc + ((size_t)(ktg * 32 + nt0 + n) * 64 + lane) * 8);
  }
#pragma unroll
  for (int g = 0; g < 16; ++g)
#pragma unroll
    for (int n = 0; n < 2; ++n) asm volatile("" : "+v"(br[g][n]));

  // ---- t = 0: h0 = tanh(pre0) on own cols. read-all / barrier / write.
  float v0[8];
#pragma unroll
  for (int i = 0; i < 8; ++i) {
    int idx = i * 512 + tid;                 // 16 rows x 256 cols
    int row = idx >> 8, col = idx & 255;
    v0[i] = buf[(size_t)(b0 + row) * TH + C0 + col];
  }
  __syncthreads();
#pragma unroll
  for (int i = 0; i < 8; ++i) {
    int idx = i * 512 + tid;
    int row = idx >> 8, col = idx & 255;
    float h = fast_tanh(v0[i]);
    unsigned short hb = f2bf(h);
    hbuf[(size_t)(b0 + row) * (size_t)NT * 1024 + 256 + C0 + col] = hb;
    h_lds[0][(row * 256 + col) ^ ((row & 7) << 3)] = hb;
  }
  __threadfence();
  __syncthreads();
  if (tid == 0) __hip_atomic_store(flagO, 0, __ATOMIC_RELEASE, __HIP_MEMORY_SCOPE_AGENT);

  // ---- per-lane pointers ----
  // partner A-frags: row (b0+arow), u16 col 256 + Cp + kl*32 + bb*8, at h-row t-1
  const unsigned short* pPa =
      hbuf + (size_t)(b0 + arow) * (size_t)NT * 1024 + 256 + Cp + bb * 8;
  // own pre (fp32), rows b0+bb*4+r, cols C0+cw0+arow (+n*16), starting at t=1
  const float* pPre[4];
  unsigned short* pSt[4];
#pragma unroll
  for (int r = 0; r < 4; ++r) {
    int b = b0 + bb * 4 + r;
    pPre[r] = buf + (size_t)b * TH + 512 + C0 + cw0 + arow;
    pSt[r]  = hbuf + (size_t)b * (size_t)NT * 1024 + 1024 + 256 + C0 + cw0 + arow;
  }

  // preload pre(t=1)
  float pre[8];
#pragma unroll
  for (int n = 0; n < 2; ++n)
#pragma unroll
    for (int r = 0; r < 4; ++r) pre[n * 4 + r] = pPre[r][n * 16];

#pragma unroll 1
  for (int t = 1; t < NT; ++t) {
    // 0) wait for partner h(t-1) (usually already posted -> single check)
    {
      const int want = t - 1;
      while (__hip_atomic_load(flagP, __ATOMIC_ACQUIRE, __HIP_MEMORY_SCOPE_AGENT) < want)
        __builtin_amdgcn_s_sleep(1);
    }

    // 1) issue partner A-frag loads (latency hides under own-half MFMA phase)
    bf16x8 pa[8];
#pragma unroll
    for (int kl = 0; kl < 8; ++kl) pa[kl] = ld_frag(pPa + kl * 32);

    // 2) acc <- pre(t); then issue pre(t+1) loads (after partner loads in the
    //    VMEM queue, so partner-frag waits never chain behind them)
    f32x4 acc[2];
#pragma unroll
    for (int n = 0; n < 2; ++n)
#pragma unroll
      for (int r = 0; r < 4; ++r) acc[n][r] = pre[n * 4 + r];
    if (t < NT - 1) {
#pragma unroll
      for (int r = 0; r < 4; ++r) pPre[r] += 512;
#pragma unroll
      for (int n = 0; n < 2; ++n)
#pragma unroll
        for (int r = 0; r < 4; ++r) pre[n * 4 + r] = pPre[r][n * 16];
    }

    // 3) own-half MFMA: A from h_lds (written+barriered last step)
    const unsigned short* hs = h_lds[(t - 1) & 1];
#pragma unroll
    for (int kl = 0; kl < 8; ++kl) {
      bf16x8 a = ld_frag(hs + ((arow * 256 + kl * 32 + bb * 8) ^ swz));
      acc[0] = __builtin_amdgcn_mfma_f32_16x16x32_bf16(
          a, __builtin_bit_cast(bf16x8, br[kl][0]), acc[0], 0, 0, 0);
      acc[1] = __builtin_amdgcn_mfma_f32_16x16x32_bf16(
          a, __builtin_bit_cast(bf16x8, br[kl][1]), acc[1], 0, 0, 0);
    }
    // 4) partner-half MFMA: A direct from global loads
#pragma unroll
    for (int kl = 0; kl < 8; ++kl) {
      acc[0] = __builtin_amdgcn_mfma_f32_16x16x32_bf16(
          pa[kl], __builtin_bit_cast(bf16x8, br[8 + kl][0]), acc[0], 0, 0, 0);
      acc[1] = __builtin_amdgcn_mfma_f32_16x16x32_bf16(
          pa[kl], __builtin_bit_cast(bf16x8, br[8 + kl][1]), acc[1], 0, 0, 0);
    }

    // 5) epilogue: tanh -> bf16 -> global (P3 input + partner exchange) + LDS
    unsigned short* hdst = h_lds[t & 1];
#pragma unroll
    for (int n = 0; n < 2; ++n)
#pragma unroll
      for (int r = 0; r < 4; ++r) {
        int b = bb * 4 + r;
        float h = fast_tanh(acc[n][r]);
        unsigned short hb = f2bf(h);
        pSt[r][n * 16] = hb;
        hdst[(b * 256 + cw0 + n * 16 + arow) ^ ((b & 7) << 3)] = hb;
      }
#pragma unroll
    for (int r = 0; r < 4; ++r) pSt[r] += 1024;
    pPa += 1024;

    // 6) publish h(t): per-wave device fence, WG barrier, single release flag
    __threadfence();
    __syncthreads();
    if (tid == 0) __hip_atomic_store(flagO, t, __ATOMIC_RELEASE, __HIP_MEMORY_SCOPE_AGENT);
  }
}

// ---------------- launch ----------------
extern "C" void kernel_launch(void* const* d_in, const int* in_sizes, int n_in,
                              void* d_out, int out_size, void* d_ws, size_t ws_size,
                              hipStream_t stream) {
  const float* emb  = (const float*)d_in[0];
  const float* ll   = (const float*)d_in[1];
  const float* Whx  = (const float*)d_in[2];
  const float* bhx  = (const float*)d_in[3];
  const float* Wyh  = (const float*)d_in[4];
  const float* byh  = (const float*)d_in[5];
  const float* Wout = (const float*)d_in[6];
  const float* bout = (const float*)d_in[7];

  float* buf  = (float*)d_out;                       // [B*T, 512] pre -> h -> y (in place)
  float* last = buf + (size_t)NB * NT * NO;          // [B, O] tail

  char* ws = (char*)d_ws;                            // ~2.7 MB used
  unsigned short* fragWhx  = (unsigned short*)ws;                         // 512KB
  unsigned short* fragWc   = (unsigned short*)(ws + (512 * 512 * 2));     // 512KB
  unsigned short* fragWout = (unsigned short*)(ws + 2 * (512 * 512 * 2)); // 512KB
  float* z0      = (float*)(ws + 3 * (512 * 512 * 2));                    // 128KB
  float* bias_t0 = z0 + NB * NH;
  float* bias_t  = bias_t0 + NH;
  float* Wc_f32  = bias_t + NH;                                           // 1MB
  int*   flags   = (int*)(Wc_f32 + 512 * 512);                            // 512B

  k_bias<<<1, 512, 0, stream>>>(Wyh, bout, bhx, byh, bias_t0, bias_t, flags);
  k_z0<<<64, 512, 0, stream>>>(ll, Wyh, z0);
  k_wc<<<512, 512, 0, stream>>>(Wyh, Wout, Wc_f32);
  k_frag<<<128, 256, 0, stream>>>(Whx, fragWhx);     // Bm[d][j] = Whx[j][d]
  k_frag<<<128, 256, 0, stream>>>(Wc_f32, fragWc);   // Bm[k][j] = Wc[j][k]
  k_frag<<<128, 256, 0, stream>>>(Wout, fragWout);   // Bm[k][o] = Wout[o][k]

  // P1: pre = emb @ Whx^T + biases (t==0 rows get z0)
  k_gemm<0><<<2048, 512, 0, stream>>>(emb, fragWhx, buf, bias_t0, bias_t, z0, bout, last);
  // P2: sequential scan (8 WGs, paired N-split), h (bf16) in place over pre
  k_scan<<<8, 512, 0, stream>>>(buf, fragWc, flags);
  // P3: y = h @ Wout^T + bout, in place over h; also fills `last`
  k_gemm<1><<<2048, 512, 0, stream>>>(buf, fragWout, buf, bias_t0, bias_t, z0, bout, last);
}

// Round 9
// 7774.163 us; speedup vs baseline: 1.8060x; 1.8060x over previous
//
#include <hip/hip_runtime.h>
#include <hip/hip_bf16.h>

// Jordan RNN restructured:
//   Wc = Wyh @ Wout  [H,H]
//   pre[b,t,:] = emb@Whx^T + bhx + byh + (t==0 ? last_logits@Wyh^T : Wyh@bout)
//   scan: h_t = tanh(pre_t + h_{t-1} @ Wc^T)     (per-batch independent)
//   y_t  = h_t @ Wout^T + bout                    (time-parallel epilogue GEMM)
//
// Scan: 4 WGs x 512 threads (8 waves, 2/SIMD, 256-reg budget/wave). Wc split:
//   kt 0..8   AGPR-resident (9 groups x 16 = 144 AGPR/wave, "+a"-pinned;
//             AGPRs cannot be rematerialized -> residency actually holds,
//             unlike the R3-R6 "+v" pins that left VGPR_Count at 128)
//   kt 9..12  streamed from L2, 2-buffer reissue-at-consume, stable mapping
//   kt 13..15 LDS-resident (96KB)
// LDS total = 96KB wc + 32KB h dbuf = 128KB (PROVEN size; R8's 160KB silently
// failed to launch -> h stayed poison -> absmax 2.84 == |y_ref - bout|).
//
// d_out row layout (1024 u16 per [b,t] row), in-place through all phases:
//   u16 [0,256) + [768,1024) : pre as bf16, PERMUTED so each scan lane's 4
//                              values are one contiguous u16x4 (P1 writes it)
//   u16 [256,768)            : h as bf16 (scan writes, P3 reads)
//   P3 overwrites the whole row with fp32 y.

#define NB 64
#define NT 2048
#define ND 512
#define NH 512
#define NO 512
#define TH (NT * NH)

typedef float f32x4 __attribute__((ext_vector_type(4)));
typedef __bf16 bf16x8 __attribute__((ext_vector_type(8)));
typedef unsigned short u16x8 __attribute__((ext_vector_type(8)));
typedef unsigned short u16x4 __attribute__((ext_vector_type(4)));

__device__ __forceinline__ unsigned short f2bf(float x) {
  unsigned u = __builtin_bit_cast(unsigned, x);
  u += 0x7FFFu + ((u >> 16) & 1u);               // RNE
  return (unsigned short)(u >> 16);
}
__device__ __forceinline__ float bf2f(unsigned short u) {
  return __builtin_bit_cast(float, (unsigned)u << 16);
}
__device__ __forceinline__ bf16x8 ld_frag(const unsigned short* p) {
  u16x8 r = *(const u16x8*)p;
  return __builtin_bit_cast(bf16x8, r);
}
__device__ __forceinline__ f32x4 ld_frag4(const unsigned short* p) {
  return *(const f32x4*)p;
}
// tanh via hardware exp2/rcp: abs err ~1e-6, inf-safe.
__device__ __forceinline__ float fast_tanh(float x) {
  float ax = __builtin_fabsf(x);
  float e = __builtin_amdgcn_exp2f(ax * 2.8853900817779268f);  // e^(2|x|)
  float r = 1.0f - 2.0f * __builtin_amdgcn_rcpf(e + 1.0f);
  return __builtin_copysignf(r, x);
}

// ---------------- prep kernels ----------------

__global__ void k_bias(const float* __restrict__ Wyh, const float* __restrict__ bout,
                       const float* __restrict__ bhx, const float* __restrict__ byh,
                       float* bias_t0, float* bias_t) {
  int j = threadIdx.x;
  const float* row = Wyh + j * NO;
  float acc = 0.f;
  for (int o = 0; o < NO; ++o) acc += row[o] * bout[o];
  bias_t0[j] = bhx[j] + byh[j];
  bias_t[j]  = bhx[j] + byh[j] + acc;
}

__global__ void k_z0(const float* __restrict__ ll, const float* __restrict__ Wyh,
                     float* z0) {
  int b = blockIdx.x, j = threadIdx.x;
  const float* row = Wyh + j * NO;
  const float* lr = ll + b * NO;
  float acc = 0.f;
  for (int o = 0; o < NO; ++o) acc += lr[o] * row[o];
  z0[b * NH + j] = acc;
}

__global__ void k_wc(const float* __restrict__ Wyh, const float* __restrict__ Wout,
                     float* Wc) {
  int j = blockIdx.x, k = threadIdx.x;
  float acc = 0.f;
  for (int o = 0; o < NO; ++o) acc += Wyh[j * NO + o] * Wout[o * NH + k];
  Wc[j * NH + k] = acc;
}

// Build MFMA B-operand fragments for Bm = src^T (src is [N=512 rows][K=512 cols]).
// Fragment for 16x16x32: lane l holds B[kt*32 + (l>>4)*8 + i][nt*16 + (l&15)], i=0..7.
__global__ void k_frag(const float* __restrict__ src, unsigned short* __restrict__ dst) {
  int gid = blockIdx.x * 256 + threadIdx.x;  // 32768 total
  int lane = gid & 63, tidx = gid >> 6;
  int nt = tidx & 31, kt = tidx >> 5;
  const float* s = src + (size_t)(nt * 16 + (lane & 15)) * 512 + kt * 32 + (lane >> 4) * 8;
  unsigned short* d = dst + (size_t)gid * 8;
#pragma unroll
  for (int i = 0; i < 8; ++i) d[i] = f2bf(s[i]);
}

// permuted pre u16 index within a 1024-u16 row, for hidden col c:
// region base = (c>>7)*128 + (c>>8)*512; within: (c&15)*8 + ((c>>4)&7)
// -> regions [0,128),[128,256),[768,896),[896,1024); h keeps [256,768).
__device__ __forceinline__ int pre_idx(int col) {
  int w = col >> 7;
  return w * 128 + ((w >> 1) << 9) + (col & 15) * 8 + ((col >> 4) & 7);
}

// ---------------- big GEMM (P1 and P3) ----------------
// MODE 0 (P1): A fp32 (emb); out = bf16 pre in permuted u16 layout
// MODE 1 (P3): A bf16 h at u16 [256,768) of each row; out = fp32 y (full row);
//              in-place (A aliases out); t==T-1 rows -> last[]
template <int MODE>
__global__ __launch_bounds__(512) void k_gemm(
    const void* __restrict__ Ain, const unsigned short* __restrict__ fragB,
    float* __restrict__ out, const float* __restrict__ bias_t0,
    const float* __restrict__ bias_t, const float* __restrict__ z0,
    const float* __restrict__ bout, float* __restrict__ last) {
  __shared__ __align__(16) unsigned short a_lds[64 * 512];  // 64KB, XOR-swizzled bf16
  int tid = threadIdx.x;
  long bt0 = (long)blockIdx.x * 64;

  if (MODE == 0) {
    const float* A = (const float*)Ain;
#pragma unroll
    for (int it = 0; it < 16; ++it) {
      int chunk = it * 512 + tid;
      int r = chunk >> 7, c4 = chunk & 127;
      float4 v = ((const float4*)A)[(bt0 + r) * 128 + c4];
      int idx = (r * 512 + c4 * 4) ^ ((r & 7) << 3);
      unsigned short* p = &a_lds[idx];
      p[0] = f2bf(v.x); p[1] = f2bf(v.y); p[2] = f2bf(v.z); p[3] = f2bf(v.w);
    }
  } else {
    const unsigned short* A = (const unsigned short*)Ain;
#pragma unroll
    for (int it = 0; it < 8; ++it) {
      int chunk = it * 512 + tid;           // 4096 chunks of 8 u16
      int r = chunk >> 6, c8 = chunk & 63;
      u16x8 v = *(const u16x8*)(A + (size_t)(bt0 + r) * 1024 + 256 + c8 * 8);
      int idx = (r * 512 + c8 * 8) ^ ((r & 7) << 3);
      *(u16x8*)&a_lds[idx] = v;
    }
  }
  __syncthreads();

  int wave = tid >> 6, lane = tid & 63;
  int r0 = (wave & 3) * 16, c0 = (wave >> 2) * 256;
  f32x4 acc[16];
#pragma unroll
  for (int n = 0; n < 16; ++n) acc[n] = (f32x4){0.f, 0.f, 0.f, 0.f};
  int arow = r0 + (lane & 15);

  for (int kt = 0; kt < 16; ++kt) {
    int aidx = (arow * 512 + kt * 32 + (lane >> 4) * 8) ^ ((arow & 7) << 3);
    bf16x8 a = ld_frag(&a_lds[aidx]);
    const unsigned short* bp = fragB + ((size_t)(kt * 32 + (c0 >> 4)) * 64 + lane) * 8;
#pragma unroll
    for (int n = 0; n < 16; ++n) {
      bf16x8 b = ld_frag(bp + (size_t)n * 512);
      acc[n] = __builtin_amdgcn_mfma_f32_16x16x32_bf16(a, b, acc[n], 0, 0, 0);
    }
  }

#pragma unroll
  for (int n = 0; n < 16; ++n) {
    int col = c0 + n * 16 + (lane & 15);
#pragma unroll
    for (int reg = 0; reg < 4; ++reg) {
      long row = bt0 + r0 + (lane >> 4) * 4 + reg;
      float v = acc[n][reg];
      if (MODE == 0) {
        int t = (int)(row & (NT - 1));
        long b = row >> 11;
        v += (t == 0) ? (bias_t0[col] + z0[b * NH + col]) : bias_t[col];
        ((unsigned short*)out)[row * 1024 + pre_idx(col)] = f2bf(v);
      } else {
        v += bout[col];
        out[row * 512 + col] = v;
        if ((row & (NT - 1)) == NT - 1) last[(row >> 11) * 512 + col] = v;
      }
    }
  }
}

// ---------------- sequential scan ----------------
// grid 4 x 512 threads; WG w owns batches [16w, 16w+16). No inter-WG sync.
__global__ __launch_bounds__(512, 2) void k_scan(float* __restrict__ buf,
                                                 const unsigned short* __restrict__ fragWc) {
  __shared__ __align__(16) unsigned short h_lds[2][16 * 512];   // 32KB
  __shared__ __align__(16) unsigned short wc_lds[8 * 12 * 512]; // 96KB: kt13..15
  unsigned short* hbuf = (unsigned short*)buf;
  const int tid = threadIdx.x;
  const int b0 = blockIdx.x * 16;
  const int wave = tid >> 6, lane = tid & 63;
  const int arow = lane & 15, bb = lane >> 4;
  const int c0 = wave * 64;
  const int swz = (arow & 7) << 3;
  const int w2 = wave >> 1;
  const int poff = w2 * 128 + ((w2 >> 1) << 9) + arow * 8 + (wave & 1) * 4;

  const unsigned short* bW = fragWc + ((size_t)(wave * 4) * 64 + lane) * 8;

  // ---- Wc kt=13..15 -> LDS (once) ----
#pragma unroll
  for (int g = 0; g < 3; ++g)
#pragma unroll
    for (int n = 0; n < 4; ++n) {
      f32x4 v = ld_frag4(bW + (size_t)((13 + g) * 32 + n) * 512);
      *(f32x4*)&wc_lds[(size_t)((wave * 3 + g) * 4 + n) * 512 + lane * 8] = v;
    }

  // ---- Wc kt=0..8 -> AGPRs (144/wave). "+a" pins the values in the AGPR
  //      file; unlike "+v" (R3-R6), AGPR contents can't be rematerialized
  //      as loop-invariant L2 loads, so residency actually holds.
  f32x4 ba[9][4];
#pragma unroll
  for (int g = 0; g < 9; ++g)
#pragma unroll
    for (int n = 0; n < 4; ++n) ba[g][n] = ld_frag4(bW + (size_t)(g * 32 + n) * 512);
#pragma unroll
  for (int g = 0; g < 9; ++g)
#pragma unroll
    for (int n = 0; n < 4; ++n) asm volatile("" : "+a"(ba[g][n]));

  // ---- t = 0: h0 = tanh(pre0). pre region [0,256)+[768,1024) is disjoint
  //      from the h region [256,768), so no read/write hazard, no barrier.
  u16x4 pr[4];
#pragma unroll
  for (int r = 0; r < 4; ++r)
    pr[r] = *(const u16x4*)(hbuf + (size_t)(b0 + bb * 4 + r) * (size_t)(NT * 1024) + poff);
#pragma unroll
  for (int r = 0; r < 4; ++r)
#pragma unroll
    for (int n = 0; n < 4; ++n) {
      float h = fast_tanh(bf2f(pr[r][n]));
      unsigned short hb = f2bf(h);
      int b = bb * 4 + r, col = c0 + n * 16 + arow;
      hbuf[(size_t)(b0 + b) * (size_t)(NT * 1024) + 256 + col] = hb;
      h_lds[0][(b * 512 + col) ^ ((b & 7) << 3)] = hb;
    }

  // per-lane global pointers at the t=1 row
  const unsigned short* pPre[4];
  unsigned short* pSt[4];
#pragma unroll
  for (int r = 0; r < 4; ++r) {
    size_t base = (size_t)(b0 + bb * 4 + r) * (size_t)(NT * 1024) + 1024;
    pPre[r] = hbuf + base + poff;
    pSt[r]  = hbuf + base + 256 + c0 + arow;
  }
  // preload pre(t=1)
#pragma unroll
  for (int r = 0; r < 4; ++r) pr[r] = *(const u16x4*)pPre[r];

  // stream prologue: q0 <- kt9, q1 <- kt10
  bf16x8 q0[4], q1[4];
#pragma unroll
  for (int n = 0; n < 4; ++n) q0[n] = ld_frag(bW + (size_t)(9 * 32 + n) * 512);
#pragma unroll
  for (int n = 0; n < 4; ++n) q1[n] = ld_frag(bW + (size_t)(10 * 32 + n) * 512);

  __syncthreads();  // h_lds[0] + wc_lds visible to all waves

#define AIDX(k) ((arow * 512 + (k) * 32 + bb * 8) ^ swz)
#define AGPR_STEP(G)                                                            \
  {                                                                             \
    bf16x8 a = ld_frag(hs + AIDX(G));                                           \
    _Pragma("unroll") for (int n = 0; n < 4; ++n)                               \
        acc[n] = __builtin_amdgcn_mfma_f32_16x16x32_bf16(                       \
            a, __builtin_bit_cast(bf16x8, ba[G][n]), acc[n], 0, 0, 0);          \
  }
// consume buffer Q against h-fragment kt=KT, then reissue Q <- group RKT
#define STREAM_STEP(Q, KT, RKT)                                                 \
  {                                                                             \
    bf16x8 a = ld_frag(hs + AIDX(KT));                                          \
    _Pragma("unroll") for (int n = 0; n < 4; ++n)                               \
        acc[n] = __builtin_amdgcn_mfma_f32_16x16x32_bf16(a, Q[n], acc[n], 0, 0, 0); \
    _Pragma("unroll") for (int n = 0; n < 4; ++n)                               \
        Q[n] = ld_frag(bWs + (size_t)((RKT) * 32 + n) * 512);                   \
  }
#define LDS_STEP(G)                                                             \
  {                                                                             \
    bf16x8 a = ld_frag(hs + AIDX(13 + G));                                      \
    _Pragma("unroll") for (int n = 0; n < 4; ++n) {                             \
      bf16x8 b = ld_frag(&wc_lds[(size_t)((wave * 3 + (G)) * 4 + n) * 512 + lane * 8]); \
      acc[n] = __builtin_amdgcn_mfma_f32_16x16x32_bf16(a, b, acc[n], 0, 0, 0);  \
    }                                                                           \
  }

#pragma unroll 1
  for (int t = 1; t < NT; ++t) {
    // launder the stream base pointer so LICM can't hoist the reissue loads
    const unsigned short* bWs = bW;
    asm volatile("" : "+v"(bWs));

    f32x4 acc[4];
#pragma unroll
    for (int n = 0; n < 4; ++n)
#pragma unroll
      for (int r = 0; r < 4; ++r) acc[n][r] = bf2f(pr[r][n]);

    const unsigned short* hs = h_lds[(t - 1) & 1];

    // MFMA order is accumulation-commutative; stream consumes are spread so
    // each reissue has >=400cy before its next consume.
    AGPR_STEP(0) AGPR_STEP(1) AGPR_STEP(2) AGPR_STEP(3)
    STREAM_STEP(q0, 9, 11)          // reissue q0 <- kt11 (consumed this step)
    AGPR_STEP(4) AGPR_STEP(5) AGPR_STEP(6) AGPR_STEP(7)
    STREAM_STEP(q1, 10, 12)         // reissue q1 <- kt12 (consumed this step)
    AGPR_STEP(8)
    LDS_STEP(0)
    STREAM_STEP(q0, 11, 9)          // reissue q0 <- kt9  (next step)
    LDS_STEP(1)
    STREAM_STEP(q1, 12, 10)         // reissue q1 <- kt10 (next step)
    LDS_STEP(2)

    // pre(t+1): issued AFTER all stream loads of this step (in-order vmcnt)
    if (t < NT - 1) {
#pragma unroll
      for (int r = 0; r < 4; ++r) {
        pPre[r] += 1024;
        pr[r] = *(const u16x4*)pPre[r];
      }
    }

    // epilogue: tanh -> bf16 h -> global (P3 input) + LDS (next step's A)
    unsigned short* hdst = h_lds[t & 1];
#pragma unroll
    for (int n = 0; n < 4; ++n)
#pragma unroll
      for (int r = 0; r < 4; ++r) {
        int b = bb * 4 + r;
        float h = fast_tanh(acc[n][r]);
        unsigned short hb = f2bf(h);
        pSt[r][n * 16] = hb;
        hdst[(b * 512 + c0 + n * 16 + arow) ^ ((b & 7) << 3)] = hb;
      }
#pragma unroll
    for (int r = 0; r < 4; ++r) pSt[r] += 1024;

    // lgkm-only drain + raw barrier: LDS h-exchange synced; global loads/stores
    // (stream reissues, pre prefetch, h stores) stay in flight across steps.
    asm volatile("s_waitcnt lgkmcnt(0)" ::: "memory");
    __builtin_amdgcn_s_barrier();
    asm volatile("" ::: "memory");
  }
#undef LDS_STEP
#undef STREAM_STEP
#undef AGPR_STEP
#undef AIDX
}

// ---------------- launch ----------------
extern "C" void kernel_launch(void* const* d_in, const int* in_sizes, int n_in,
                              void* d_out, int out_size, void* d_ws, size_t ws_size,
                              hipStream_t stream) {
  const float* emb  = (const float*)d_in[0];
  const float* ll   = (const float*)d_in[1];
  const float* Whx  = (const float*)d_in[2];
  const float* bhx  = (const float*)d_in[3];
  const float* Wyh  = (const float*)d_in[4];
  const float* byh  = (const float*)d_in[5];
  const float* Wout = (const float*)d_in[6];
  const float* bout = (const float*)d_in[7];

  float* buf  = (float*)d_out;                       // [B*T, 512] pre/h -> y (in place)
  float* last = buf + (size_t)NB * NT * NO;          // [B, O] tail

  char* ws = (char*)d_ws;                            // ~2.7 MB used
  unsigned short* fragWhx  = (unsigned short*)ws;                         // 512KB
  unsigned short* fragWc   = (unsigned short*)(ws + (512 * 512 * 2));     // 512KB
  unsigned short* fragWout = (unsigned short*)(ws + 2 * (512 * 512 * 2)); // 512KB
  float* z0      = (float*)(ws + 3 * (512 * 512 * 2));                    // 128KB
  float* bias_t0 = z0 + NB * NH;
  float* bias_t  = bias_t0 + NH;
  float* Wc_f32  = bias_t + NH;                                           // 1MB

  k_bias<<<1, 512, 0, stream>>>(Wyh, bout, bhx, byh, bias_t0, bias_t);
  k_z0<<<64, 512, 0, stream>>>(ll, Wyh, z0);
  k_wc<<<512, 512, 0, stream>>>(Wyh, Wout, Wc_f32);
  k_frag<<<128, 256, 0, stream>>>(Whx, fragWhx);     // Bm[d][j] = Whx[j][d]
  k_frag<<<128, 256, 0, stream>>>(Wc_f32, fragWc);   // Bm[k][j] = Wc[j][k]
  k_frag<<<128, 256, 0, stream>>>(Wout, fragWout);   // Bm[k][o] = Wout[o][k]

  // P1: pre = emb @ Whx^T + biases -> bf16 permuted layout (t==0 rows get z0)
  k_gemm<0><<<2048, 512, 0, stream>>>(emb, fragWhx, buf, bias_t0, bias_t, z0, bout, last);
  // P2: sequential scan, h (bf16) written into u16 [256,768) of each row
  k_scan<<<4, 512, 0, stream>>>(buf, fragWc);
  // P3: y = h @ Wout^T + bout, in place; also fills `last`
  k_gemm<1><<<2048, 512, 0, stream>>>(buf, fragWout, buf, bias_t0, bias_t, z0, bout, last);
}